// Round 2
// baseline (439.610 us; speedup 1.0000x reference)
//
#include <hip/hip_runtime.h>

#define NLINES 320
#define PSLOPE 5.0f

// ---------------- threefry2x32, 20 rounds (JAX-compatible) ----------------
__device__ __forceinline__ unsigned rotl32(unsigned x, int r) {
    return (x << r) | (x >> (32 - r));
}

__device__ __forceinline__ void tf2x32(unsigned k0, unsigned k1,
                                       unsigned x0, unsigned x1,
                                       unsigned& o0, unsigned& o1) {
    unsigned ks2 = k0 ^ k1 ^ 0x1BD11BDAu;
    x0 += k0; x1 += k1;
#define TFR(r) { x0 += x1; x1 = rotl32(x1, r); x1 ^= x0; }
    TFR(13) TFR(15) TFR(26) TFR(6)
    x0 += k1;  x1 += ks2 + 1u;
    TFR(17) TFR(29) TFR(16) TFR(24)
    x0 += ks2; x1 += k0 + 2u;
    TFR(13) TFR(15) TFR(26) TFR(6)
    x0 += k0;  x1 += k1 + 3u;
    TFR(17) TFR(29) TFR(16) TFR(24)
    x0 += k1;  x1 += ks2 + 4u;
    TFR(13) TFR(15) TFR(26) TFR(6)
    x0 += ks2; x1 += k0 + 5u;
#undef TFR
    o0 = x0; o1 = x1;
}

// JAX uniform: bitcast((bits >> 9) | 0x3F800000) - 1.0
__device__ __forceinline__ float u01f(unsigned bits) {
    return __uint_as_float((bits >> 9) | 0x3F800000u) - 1.0f;
}

// ---------------- mask construction: 1 block x 320 threads ----------------
// Implements: sigmoid -> RescaleProbMap -> threefry rejection sampling
// (jax_threefry_partitionable=True semantics):
//   split:   key' = H(key,(0,0)), sub = H(key,(0,1))   [fold-like]
//   bits[i]: H(sub,(0,i)) -> o0 ^ o1                   [per-element counter]
__global__ __launch_bounds__(NLINES)
void build_mask(const float* __restrict__ logits,
                const float* __restrict__ sparsity_p,
                float* __restrict__ mask_out) {
    __shared__ float wred[5];
    __shared__ int   wcnt[5];
    __shared__ float bc[2];
    const int tid  = threadIdx.x;
    const int wave = tid >> 6;
    const int lane = tid & 63;

    // prob mask
    const float p = 1.0f / (1.0f + expf(-PSLOPE * logits[tid]));

    // xbar = mean(p)
    float s = p;
#pragma unroll
    for (int off = 32; off; off >>= 1) s += __shfl_down(s, off, 64);
    if (lane == 0) wred[wave] = s;
    __syncthreads();                               // (A)
    if (tid == 0) bc[0] = wred[0] + wred[1] + wred[2] + wred[3] + wred[4];
    __syncthreads();                               // (B)
    const float xbar = bc[0] / (float)NLINES;

    // rescale
    const float sp   = sparsity_p[0];
    const float r    = sp / xbar;
    const float beta = (1.0f - sp) / (1.0f - xbar);
    const float xv   = (r <= 1.0f) ? (p * r) : (1.0f - (1.0f - p) * beta);

    // xm = mean(xv)
    float s2 = xv;
#pragma unroll
    for (int off = 32; off; off >>= 1) s2 += __shfl_down(s2, off, 64);
    if (lane == 0) wred[wave] = s2;                // safe: tid0 read was before (B)
    __syncthreads();                               // (C)
    if (tid == 0) bc[1] = wred[0] + wred[1] + wred[2] + wred[3] + wred[4];
    __syncthreads();                               // (D)
    const float xm = bc[1] / (float)NLINES;

    // rejection sampling loop, key = jax.random.key(42) = (0, 42)
    unsigned k0 = 0u, k1 = 42u;
    float mline = 0.0f;
    for (int it = 0; it < 8192; ++it) {
        unsigned nk0, nk1, s0, s1;
        tf2x32(k0, k1, 0u, 0u, nk0, nk1);          // carry key
        tf2x32(k0, k1, 0u, 1u, s0, s1);            // sub key
        unsigned o0, o1;
        tf2x32(s0, s1, 0u, (unsigned)tid, o0, o1); // per-line bits
        const float prob = u01f(o0 ^ o1);
        const int   res  = (xv > prob) ? 1 : 0;

        unsigned long long bal = __ballot(res != 0);
        if (lane == 0) wcnt[wave] = (int)__popcll(bal);
        __syncthreads();
        const int count = wcnt[0] + wcnt[1] + wcnt[2] + wcnt[3] + wcnt[4];
        const float meanr = (float)count / (float)NLINES;
        mline = (float)res;
        // torch.isclose-style: |meanr - xm| <= atol + rtol*|xm|  (block-uniform)
        const bool ok = fabsf(meanr - xm) <= (1e-3f + 1e-5f * fabsf(xm));
        if (ok) break;
        k0 = nk0; k1 = nk1;
        __syncthreads();                           // protect wcnt reuse
    }

    // force-include outermost lines (applied after binarize in reference)
    if (tid == 0 || tid == NLINES - 1) mline = 1.0f;
    mask_out[tid] = mline;
}

// ---------------- output streaming: float4, skip loads on masked lines ----
#define NK4 13107200   // 256*2*320*320 / 4
#define NM4 6553600    // 256*1*320*320 / 4
#define NT4 19660800   // NK4 + NM4

__global__ __launch_bounds__(256)
void apply_mask(const float4* __restrict__ k4,
                const float* __restrict__ mask,
                float4* __restrict__ out4) {
    const int i = blockIdx.x * 256 + threadIdx.x;
    if (i < NK4) {
        const int h = (i / 80) % 320;              // 80 float4 per 320-wide line
        const float m = mask[h];
        float4 v = make_float4(0.f, 0.f, 0.f, 0.f);
        if (m != 0.0f) v = k4[i];                  // skip HBM read of zeroed lines
        out4[i] = v;
    } else {
        const int j = i - NK4;
        const int h = (j / 80) % 320;
        const float m = mask[h];
        out4[i] = make_float4(m, m, m, m);
    }
}

extern "C" void kernel_launch(void* const* d_in, const int* in_sizes, int n_in,
                              void* d_out, int out_size, void* d_ws, size_t ws_size,
                              hipStream_t stream) {
    const float* kspace   = (const float*)d_in[0];   // (256,2,320,320) f32
    const float* sparsity = (const float*)d_in[1];   // scalar
    const float* logits   = (const float*)d_in[2];   // (320,) f32
    float* mask = (float*)d_ws;                      // 320 floats scratch
    float* out  = (float*)d_out;                     // masked_kspace ++ mask_full

    hipLaunchKernelGGL(build_mask, dim3(1), dim3(NLINES), 0, stream,
                       logits, sparsity, mask);
    hipLaunchKernelGGL(apply_mask, dim3(NT4 / 256), dim3(256), 0, stream,
                       (const float4*)kspace, mask, (float4*)out);
}

// Round 4
// 439.520 us; speedup vs baseline: 1.0002x; 1.0002x over previous
//
#include <hip/hip_runtime.h>

#define NLINES 320
#define PSLOPE 5.0f

typedef float nfloat4 __attribute__((ext_vector_type(4)));  // NT-builtin-compatible

// ---------------- threefry2x32, 20 rounds (JAX-compatible) ----------------
__device__ __forceinline__ unsigned rotl32(unsigned x, int r) {
    return (x << r) | (x >> (32 - r));
}

__device__ __forceinline__ void tf2x32(unsigned k0, unsigned k1,
                                       unsigned x0, unsigned x1,
                                       unsigned& o0, unsigned& o1) {
    unsigned ks2 = k0 ^ k1 ^ 0x1BD11BDAu;
    x0 += k0; x1 += k1;
#define TFR(r) { x0 += x1; x1 = rotl32(x1, r); x1 ^= x0; }
    TFR(13) TFR(15) TFR(26) TFR(6)
    x0 += k1;  x1 += ks2 + 1u;
    TFR(17) TFR(29) TFR(16) TFR(24)
    x0 += ks2; x1 += k0 + 2u;
    TFR(13) TFR(15) TFR(26) TFR(6)
    x0 += k0;  x1 += k1 + 3u;
    TFR(17) TFR(29) TFR(16) TFR(24)
    x0 += k1;  x1 += ks2 + 4u;
    TFR(13) TFR(15) TFR(26) TFR(6)
    x0 += ks2; x1 += k0 + 5u;
#undef TFR
    o0 = x0; o1 = x1;
}

// JAX uniform: bitcast((bits >> 9) | 0x3F800000) - 1.0
__device__ __forceinline__ float u01f(unsigned bits) {
    return __uint_as_float((bits >> 9) | 0x3F800000u) - 1.0f;
}

// ---------------- mask construction: 1 block x 320 threads ----------------
// jax_threefry_partitionable=True semantics, verified exact in R2 (absmax=0):
//   split:   key' = H(key,(0,0)), sub = H(key,(0,1))
//   bits[i]: H(sub,(0,i)) -> o0 ^ o1
__global__ __launch_bounds__(NLINES)
void build_mask(const float* __restrict__ logits,
                const float* __restrict__ sparsity_p,
                float* __restrict__ mask_out) {
    __shared__ float wred[5];
    __shared__ int   wcnt[5];
    __shared__ float bc[2];
    const int tid  = threadIdx.x;
    const int wave = tid >> 6;
    const int lane = tid & 63;

    // prob mask
    const float p = 1.0f / (1.0f + expf(-PSLOPE * logits[tid]));

    // xbar = mean(p)
    float s = p;
#pragma unroll
    for (int off = 32; off; off >>= 1) s += __shfl_down(s, off, 64);
    if (lane == 0) wred[wave] = s;
    __syncthreads();                               // (A)
    if (tid == 0) bc[0] = wred[0] + wred[1] + wred[2] + wred[3] + wred[4];
    __syncthreads();                               // (B)
    const float xbar = bc[0] / (float)NLINES;

    // rescale
    const float sp   = sparsity_p[0];
    const float r    = sp / xbar;
    const float beta = (1.0f - sp) / (1.0f - xbar);
    const float xv   = (r <= 1.0f) ? (p * r) : (1.0f - (1.0f - p) * beta);

    // xm = mean(xv)
    float s2 = xv;
#pragma unroll
    for (int off = 32; off; off >>= 1) s2 += __shfl_down(s2, off, 64);
    if (lane == 0) wred[wave] = s2;
    __syncthreads();                               // (C)
    if (tid == 0) bc[1] = wred[0] + wred[1] + wred[2] + wred[3] + wred[4];
    __syncthreads();                               // (D)
    const float xm = bc[1] / (float)NLINES;

    // rejection sampling loop, key = jax.random.key(42) = (0, 42)
    unsigned k0 = 0u, k1 = 42u;
    float mline = 0.0f;
    for (int it = 0; it < 8192; ++it) {
        unsigned nk0, nk1, s0, s1;
        tf2x32(k0, k1, 0u, 0u, nk0, nk1);          // carry key
        tf2x32(k0, k1, 0u, 1u, s0, s1);            // sub key
        unsigned o0, o1;
        tf2x32(s0, s1, 0u, (unsigned)tid, o0, o1); // per-line bits
        const float prob = u01f(o0 ^ o1);
        const int   res  = (xv > prob) ? 1 : 0;

        unsigned long long bal = __ballot(res != 0);
        if (lane == 0) wcnt[wave] = (int)__popcll(bal);
        __syncthreads();
        const int count = wcnt[0] + wcnt[1] + wcnt[2] + wcnt[3] + wcnt[4];
        const float meanr = (float)count / (float)NLINES;
        mline = (float)res;
        const bool ok = fabsf(meanr - xm) <= (1e-3f + 1e-5f * fabsf(xm));
        if (ok) break;
        k0 = nk0; k1 = nk1;
        __syncthreads();                           // protect wcnt reuse
    }

    // force-include outermost lines
    if (tid == 0 || tid == NLINES - 1) mline = 1.0f;
    mask_out[tid] = mline;
}

// ---------------- output streaming ----------------
// 314.6 MB writes (mandatory) + ~54 MB mask-selected reads. NT stores:
// pure streaming, zero reuse, out >> L2 — skip L2 write-allocate pressure.
#define NK4 13107200   // 256*2*320*320 / 4
#define NM4 6553600    // 256*1*320*320 / 4
#define NT4 19660800   // NK4 + NM4

__global__ __launch_bounds__(256)
void apply_mask(const nfloat4* __restrict__ k4,
                const float* __restrict__ mask,
                nfloat4* __restrict__ out4) {
    const int i = blockIdx.x * 256 + threadIdx.x;
    if (i < NK4) {
        const int h = (i / 80) % 320;              // 80 float4 per 320-wide line
        const float m = mask[h];
        nfloat4 v = (nfloat4)(0.0f);
        if (m != 0.0f) v = k4[i];                  // skip HBM read of zeroed lines
        __builtin_nontemporal_store(v, &out4[i]);
    } else {
        const int j = i - NK4;
        const int h = (j / 80) % 320;
        const float m = mask[h];
        __builtin_nontemporal_store((nfloat4)(m), &out4[i]);
    }
}

extern "C" void kernel_launch(void* const* d_in, const int* in_sizes, int n_in,
                              void* d_out, int out_size, void* d_ws, size_t ws_size,
                              hipStream_t stream) {
    const float* kspace   = (const float*)d_in[0];   // (256,2,320,320) f32
    const float* sparsity = (const float*)d_in[1];   // scalar
    const float* logits   = (const float*)d_in[2];   // (320,) f32
    float* mask = (float*)d_ws;                      // 320 floats scratch
    float* out  = (float*)d_out;                     // masked_kspace ++ mask_full

    hipLaunchKernelGGL(build_mask, dim3(1), dim3(NLINES), 0, stream,
                       logits, sparsity, mask);
    hipLaunchKernelGGL(apply_mask, dim3(NT4 / 256), dim3(256), 0, stream,
                       (const nfloat4*)kspace, mask, (nfloat4*)out);
}